// Round 1
// baseline (443.579 us; speedup 1.0000x reference)
//
#include <hip/hip_runtime.h>

typedef unsigned short u16;
typedef __attribute__((ext_vector_type(8))) short bf16x8;
typedef __attribute__((ext_vector_type(4))) float f32x4;

// ---- constants: B=8 N=4096 C=768 H=8 D=96, M = B*N = 32768 ----
#define M_TOT 32768

__device__ __forceinline__ u16 f2b(float x) {
    union { float f; unsigned u; } c; c.f = x;
    unsigned r = c.u + 0x7fffu + ((c.u >> 16) & 1u);  // RNE
    return (u16)(r >> 16);
}

// ============================================================
// prep_b1: B1[d,k] (96 x 1536 bf16), k<768 -> w1 * sum_h W_qkv_rgb[1536+h*96+d, k]
//                                    k>=768 -> w0 * sum_h W_qkv_depth[768+h*96+d, k-768]
// fb[d] = w1 * sum_h b_qkv_rgb[1536+h*96+d] + w0 * sum_h b_qkv_depth[768+h*96+d]
// ============================================================
__global__ void prep_b1(const float* __restrict__ Wr, const float* __restrict__ Wd,
                        const float* __restrict__ br, const float* __restrict__ bd,
                        const float* __restrict__ aw,
                        u16* __restrict__ B1, float* __restrict__ fb) {
    int id = blockIdx.x * 256 + threadIdx.x;
    if (id >= 96 * 1536) return;
    int d = id / 1536, k = id - d * 1536;
    float w0 = 1.f / (1.f + __expf(-aw[0]));
    float w1 = 1.f / (1.f + __expf(-aw[1]));
    float s = 0.f, v;
    if (k < 768) {
        for (int h = 0; h < 8; h++) s += Wr[(size_t)(1536 + h * 96 + d) * 768 + k];
        v = w1 * s;
    } else {
        for (int h = 0; h < 8; h++) s += Wd[(size_t)(768 + h * 96 + d) * 768 + (k - 768)];
        v = w0 * s;
    }
    B1[id] = f2b(v);
    if (k == 0) {
        float t = 0.f;
        for (int h = 0; h < 8; h++)
            t += w1 * br[1536 + h * 96 + d] + w0 * bd[768 + h * 96 + d];
        fb[d] = t;
    }
}

// ============================================================
// prep_weff: Weff[c,d] (768 x 96 bf16) = sum_h W_out[c, h*96+d]
// ============================================================
__global__ void prep_weff(const float* __restrict__ Wo, u16* __restrict__ Weff) {
    int id = blockIdx.x * 256 + threadIdx.x;
    if (id >= 768 * 96) return;
    int c = id / 96, d = id - c * 96;
    float s = 0.f;
    for (int h = 0; h < 8; h++) s += Wo[(size_t)c * 768 + h * 96 + d];
    Weff[id] = f2b(s);
}

// ============================================================
// gemm_f v2: f(32768 x 96) = [Xr | Xd](32768 x 1536) @ B1^T + fb, bf16 out.
// LDS-free, barrier-free. Each wave owns 16 rows x all 96 cols.
// A-fragments loaded straight from global (fragment pattern = 16 rows x 128B
// dense per instruction pair), converted in-register; out0 = x_rgb passthrough
// fused with the A reads (bit-exact float4 copy). Next K-step's A is
// prefetched into registers one step ahead to hide HBM latency.
// B-fragments loaded per-wave straight from B1 (294 KB, L2-resident).
// Accumulation order per acc element identical to v1 (ks asc, s asc).
// ============================================================
__global__ __launch_bounds__(256) void gemm_f(const float* __restrict__ Xr,
                                              const float* __restrict__ Xd,
                                              const u16* __restrict__ B1,
                                              const float* __restrict__ fb,
                                              float* __restrict__ out0,
                                              u16* __restrict__ fbuf) {
    const int tid = threadIdx.x;
    const int lane = tid & 63;
    const int wv = (blockIdx.x << 2) | (tid >> 6);      // 0..2047, 16 rows each
    const int fr = lane & 15;
    const int fk = (lane >> 4) << 3;                    // 0,8,16,24
    const size_t arow = (size_t)((wv << 4) | fr) * 768 + fk;

    const float* __restrict__ pr = Xr + arow;
    const float* __restrict__ pd = Xd + arow;
    float* __restrict__ po = out0 + arow;
    const u16* __restrict__ pb = B1 + fr * 1536 + fk;

    f32x4 acc[6] = {};

    // prologue: A(0)
    float4 a0 = *(const float4*)(pr);
    float4 a1 = *(const float4*)(pr + 4);
    float4 a2 = *(const float4*)(pr + 32);
    float4 a3 = *(const float4*)(pr + 36);

    for (int ks = 0; ks < 24; ks++) {
        const int k0 = ks * 64;

        // ---- prefetch A(ks+1) (clamped dummy re-read of row start at ks=23) ----
        const float* pn = (ks >= 23) ? pr
                        : ((ks + 1 < 12) ? (pr + k0 + 64) : (pd + k0 - 704));
        float4 n0 = *(const float4*)(pn);
        float4 n1 = *(const float4*)(pn + 4);
        float4 n2 = *(const float4*)(pn + 32);
        float4 n3 = *(const float4*)(pn + 36);

        // ---- fused x_rgb passthrough (each element stored exactly once) ----
        if (ks < 12) {
            *(float4*)(po + k0)      = a0;
            *(float4*)(po + k0 + 4)  = a1;
            *(float4*)(po + k0 + 32) = a2;
            *(float4*)(po + k0 + 36) = a3;
        }

        // ---- convert fp32 -> bf16 fragments ----
        bf16x8 ab0, ab1;
        ab0[0] = (short)f2b(a0.x); ab0[1] = (short)f2b(a0.y);
        ab0[2] = (short)f2b(a0.z); ab0[3] = (short)f2b(a0.w);
        ab0[4] = (short)f2b(a1.x); ab0[5] = (short)f2b(a1.y);
        ab0[6] = (short)f2b(a1.z); ab0[7] = (short)f2b(a1.w);
        ab1[0] = (short)f2b(a2.x); ab1[1] = (short)f2b(a2.y);
        ab1[2] = (short)f2b(a2.z); ab1[3] = (short)f2b(a2.w);
        ab1[4] = (short)f2b(a3.x); ab1[5] = (short)f2b(a3.y);
        ab1[6] = (short)f2b(a3.z); ab1[7] = (short)f2b(a3.w);

        // ---- MFMA with direct-from-L2 B fragments (same acc order as v1) ----
        const u16* pbk = pb + k0;
#pragma unroll
        for (int j = 0; j < 6; j++)
            acc[j] = __builtin_amdgcn_mfma_f32_16x16x32_bf16(
                ab0, *(const bf16x8*)(pbk + j * 24576), acc[j], 0, 0, 0);
#pragma unroll
        for (int j = 0; j < 6; j++)
            acc[j] = __builtin_amdgcn_mfma_f32_16x16x32_bf16(
                ab1, *(const bf16x8*)(pbk + j * 24576 + 32), acc[j], 0, 0, 0);

        a0 = n0; a1 = n1; a2 = n2; a3 = n3;
    }

    // ---- epilogue: +bias, store bf16. C/D: row=(lane>>4)*4+r, col=lane&15 ----
    const int em = (lane >> 4) << 2, en = lane & 15;
    const int orow = (wv << 4) + em;
#pragma unroll
    for (int j = 0; j < 6; j++) {
        const int dcol = j * 16 + en;
        const float bias = fb[dcol];
#pragma unroll
        for (int r = 0; r < 4; r++)
            fbuf[(size_t)(orow + r) * 96 + dcol] = f2b(acc[j][r] + bias);
    }
}

// ============================================================
// gemm_o v2: out1(32768 x 768) = fbuf(32768 x 96 bf16) @ Weff^T + b_out (fp32).
// LDS-free, barrier-free, 16384 waves (vs 1536 LDS-limited blocks before).
// fbuf is already bf16 in exact A-fragment layout -> direct 16B loads.
// Weff (147 KB) is L2-resident. Bound only by the out1 write stream.
// ============================================================
__global__ __launch_bounds__(256) void gemm_o(const u16* __restrict__ fbuf,
                                              const u16* __restrict__ Weff,
                                              const float* __restrict__ bout,
                                              float* __restrict__ out1) {
    const int tid = threadIdx.x;
    const int lane = tid & 63;
    const int wv = (blockIdx.x << 2) | (tid >> 6);      // 0..16383
    const int mg = wv >> 3;                             // row-group 0..2047
    const int nc = (wv & 7) * 96;                       // col-chunk base
    const int fr = lane & 15, fk = (lane >> 4) << 3;

    const u16* pa = fbuf + (size_t)((mg << 4) | fr) * 96 + fk;
    bf16x8 A0 = *(const bf16x8*)(pa);
    bf16x8 A1 = *(const bf16x8*)(pa + 32);
    bf16x8 A2 = *(const bf16x8*)(pa + 64);

    const u16* pb = Weff + (size_t)(nc + fr) * 96 + fk;
    f32x4 acc[6] = {};
#pragma unroll
    for (int j = 0; j < 6; j++) {
        const u16* pbj = pb + j * 1536;                 // 16 rows x 96
        acc[j] = __builtin_amdgcn_mfma_f32_16x16x32_bf16(
            A0, *(const bf16x8*)(pbj), acc[j], 0, 0, 0);
        acc[j] = __builtin_amdgcn_mfma_f32_16x16x32_bf16(
            A1, *(const bf16x8*)(pbj + 32), acc[j], 0, 0, 0);
        acc[j] = __builtin_amdgcn_mfma_f32_16x16x32_bf16(
            A2, *(const bf16x8*)(pbj + 64), acc[j], 0, 0, 0);
    }

    const int em = (lane >> 4) << 2, en = lane & 15;
    const int orow = (mg << 4) + em;
#pragma unroll
    for (int j = 0; j < 6; j++) {
        const int col = nc + j * 16 + en;
        const float bias = bout[col];
#pragma unroll
        for (int r = 0; r < 4; r++)
            out1[(size_t)(orow + r) * 768 + col] = acc[j][r] + bias;
    }
}

// ============================================================
extern "C" void kernel_launch(void* const* d_in, const int* in_sizes, int n_in,
                              void* d_out, int out_size, void* d_ws, size_t ws_size,
                              hipStream_t stream) {
    const float* x_rgb       = (const float*)d_in[0];
    const float* x_depth     = (const float*)d_in[1];
    const float* W_qkv_rgb   = (const float*)d_in[2];
    const float* b_qkv_rgb   = (const float*)d_in[3];
    const float* W_qkv_depth = (const float*)d_in[4];
    const float* b_qkv_depth = (const float*)d_in[5];
    const float* W_out       = (const float*)d_in[6];
    const float* b_out       = (const float*)d_in[7];
    const float* aw          = (const float*)d_in[8];

    float* out0 = (float*)d_out;                      // x_rgb passthrough
    float* out1 = out0 + (size_t)M_TOT * 768;         // x_fusion

    // workspace layout (all 16B-aligned offsets); total ~6.8 MB
    char* w = (char*)d_ws;
    u16*   B1   = (u16*)w;                              // 96*1536*2   = 294912
    float* fb   = (float*)(w + 294912);                 // 96*4 (+pad) -> next at +512
    u16*   Weff = (u16*)(w + 294912 + 512);             // 768*96*2    = 147456
    u16*   fbuf = (u16*)(w + 294912 + 512 + 147456);    // 32768*96*2  = 6291456

    prep_b1<<<576, 256, 0, stream>>>(W_qkv_rgb, W_qkv_depth, b_qkv_rgb, b_qkv_depth,
                                     aw, B1, fb);
    prep_weff<<<288, 256, 0, stream>>>(W_out, Weff);
    gemm_f<<<512, 256, 0, stream>>>(x_rgb, x_depth, B1, fb, out0, fbuf);
    gemm_o<<<4096, 256, 0, stream>>>(fbuf, Weff, b_out, out1);
}

// Round 4
// 404.625 us; speedup vs baseline: 1.0963x; 1.0963x over previous
//
#include <hip/hip_runtime.h>

typedef unsigned short u16;
typedef __attribute__((ext_vector_type(8))) short bf16x8;
typedef __attribute__((ext_vector_type(4))) float f32x4;

// ---- constants: B=8 N=4096 C=768 H=8 D=96, M = B*N = 32768 ----
#define M_TOT 32768

__device__ __forceinline__ u16 f2b(float x) {
    union { float f; unsigned u; } c; c.f = x;
    unsigned r = c.u + 0x7fffu + ((c.u >> 16) & 1u);  // RNE
    return (u16)(r >> 16);
}

// raw barrier (NO implicit vmcnt drain, unlike __syncthreads) + sched pins
#define BAR() do { __builtin_amdgcn_sched_barrier(0); \
                   __builtin_amdgcn_s_barrier(); \
                   __builtin_amdgcn_sched_barrier(0); } while (0)
// ds-op visibility drain before a barrier following ds_writes
#define LGKM0() asm volatile("s_waitcnt lgkmcnt(0)" ::: "memory")

// ============================================================
// prep_b1: B1[d,k] (96 x 1536 bf16), k<768 -> w1 * sum_h W_qkv_rgb[1536+h*96+d, k]
//                                    k>=768 -> w0 * sum_h W_qkv_depth[768+h*96+d, k-768]
// fb[d] = w1 * sum_h b_qkv_rgb[1536+h*96+d] + w0 * sum_h b_qkv_depth[768+h*96+d]
// ============================================================
__global__ void prep_b1(const float* __restrict__ Wr, const float* __restrict__ Wd,
                        const float* __restrict__ br, const float* __restrict__ bd,
                        const float* __restrict__ aw,
                        u16* __restrict__ B1, float* __restrict__ fb) {
    int id = blockIdx.x * 256 + threadIdx.x;
    if (id >= 96 * 1536) return;
    int d = id / 1536, k = id - d * 1536;
    float w0 = 1.f / (1.f + __expf(-aw[0]));
    float w1 = 1.f / (1.f + __expf(-aw[1]));
    float s = 0.f, v;
    if (k < 768) {
        for (int h = 0; h < 8; h++) s += Wr[(size_t)(1536 + h * 96 + d) * 768 + k];
        v = w1 * s;
    } else {
        for (int h = 0; h < 8; h++) s += Wd[(size_t)(768 + h * 96 + d) * 768 + (k - 768)];
        v = w0 * s;
    }
    B1[id] = f2b(v);
    if (k == 0) {
        float t = 0.f;
        for (int h = 0; h < 8; h++)
            t += w1 * br[1536 + h * 96 + d] + w0 * bd[768 + h * 96 + d];
        fb[d] = t;
    }
}

// ============================================================
// prep_weff: Weff[c,d] (768 x 96 bf16) = sum_h W_out[c, h*96+d]
// ============================================================
__global__ void prep_weff(const float* __restrict__ Wo, u16* __restrict__ Weff) {
    int id = blockIdx.x * 256 + threadIdx.x;
    if (id >= 768 * 96) return;
    int c = id / 96, d = id - c * 96;
    float s = 0.f;
    for (int h = 0; h < 8; h++) s += Wo[(size_t)c * 768 + h * 96 + d];
    Weff[id] = f2b(s);
}

// ============================================================
// gemm_f v5: f(32768 x 96) = [Xr | Xd](32768 x 1536) @ B1^T + fb, bf16 out,
// + fused out0 = x_rgb passthrough.
//
// Structure = R0's proven 64-row/4-wave tile + padded LDS (LDF=72), upgraded:
//  * double-buffered LDS (buf0/buf1, static indices),
//  * depth-2 REGISTER prefetch: tile t+2's global loads issued while tile t
//    computes; committed to LDS one full phase later (T14 async-stage split),
//  * raw s_barrier (no implicit vmcnt(0) drain -> prefetch survives barriers),
//    with explicit lgkmcnt(0) before each barrier that follows ds_writes.
// All vmcnt waits are COMPILER-generated (normal loads, normal dataflow) —
// nothing here can deadlock.
//
// Hazard audit: write buf1(tile t+1) happens >=2 barriers after buf1's last
// readers (tile t-1 MFMA) finished; readers of a buffer always follow the
// writer's LGKM0+BAR. All barrier guards are block-uniform. Accumulation
// order (tiles 0..23, s=0,1, j=0..5) is bit-identical to the passing R0.
// ============================================================
#define LDF 72

__device__ __forceinline__ void stage_issue(const float* __restrict__ Xr,
                                            const float* __restrict__ Xd,
                                            const u16* __restrict__ B1,
                                            int m0, int tid, int n,
                                            float4 (&aF)[4], uint4 (&bF)[3]) {
    const float* __restrict__ X = (n < 12) ? Xr : Xd;
    const int kx = (n < 12) ? n * 64 : n * 64 - 768;
#pragma unroll
    for (int r = 0; r < 4; r++) {
        int c = tid + 256 * r, row = c >> 4, colc = (c & 15) * 4;
        aF[r] = *(const float4*)&X[(size_t)(m0 + row) * 768 + kx + colc];
    }
#pragma unroll
    for (int r = 0; r < 3; r++) {
        int c = tid + 256 * r, row = c >> 3, colc = (c & 7) * 8;
        bF[r] = *(const uint4*)&B1[(size_t)row * 1536 + n * 64 + colc];
    }
}

__device__ __forceinline__ void stage_commit(float* __restrict__ out0,
                                             int m0, int tid, int n,
                                             const float4 (&aF)[4], const uint4 (&bF)[3],
                                             u16* __restrict__ sAb, u16* __restrict__ sBb) {
#pragma unroll
    for (int r = 0; r < 4; r++) {
        int c = tid + 256 * r, row = c >> 4, colc = (c & 15) * 4;
        if (n < 12)   // fused x_rgb passthrough: each element stored exactly once
            *(float4*)&out0[(size_t)(m0 + row) * 768 + n * 64 + colc] = aF[r];
        ushort4 bv;
        bv.x = f2b(aF[r].x); bv.y = f2b(aF[r].y);
        bv.z = f2b(aF[r].z); bv.w = f2b(aF[r].w);
        *(ushort4*)&sAb[row * LDF + colc] = bv;
    }
#pragma unroll
    for (int r = 0; r < 3; r++) {
        int c = tid + 256 * r, row = c >> 3, colc = (c & 7) * 8;
        *(uint4*)&sBb[row * LDF + colc] = bF[r];
    }
}

__device__ __forceinline__ void mfma_tile(const u16* __restrict__ sAb,
                                          const u16* __restrict__ sBb,
                                          int wave, int fr, int fk, f32x4 (&acc)[6]) {
#pragma unroll
    for (int s = 0; s < 2; s++) {
        bf16x8 a = *(const bf16x8*)&sAb[(wave * 16 + fr) * LDF + s * 32 + fk];
#pragma unroll
        for (int j = 0; j < 6; j++) {
            bf16x8 b = *(const bf16x8*)&sBb[(j * 16 + fr) * LDF + s * 32 + fk];
            acc[j] = __builtin_amdgcn_mfma_f32_16x16x32_bf16(a, b, acc[j], 0, 0, 0);
        }
    }
}

__global__ __launch_bounds__(256) void gemm_f(const float* __restrict__ Xr,
                                              const float* __restrict__ Xd,
                                              const u16* __restrict__ B1,
                                              const float* __restrict__ fb,
                                              float* __restrict__ out0,
                                              u16* __restrict__ fbuf) {
    __shared__ u16 sA[2][64 * LDF];
    __shared__ u16 sB[2][96 * LDF];
    const int tid = threadIdx.x;
    const int m0 = blockIdx.x * 64;
    const int lane = tid & 63, wave = tid >> 6;
    const int fr = lane & 15, fk = (lane >> 4) * 8;

    f32x4 acc[6] = {};
    float4 a0[4], a1[4];
    uint4  b0[3], b1[3];

    // ---- prologue: issue tiles 0 and 1; commit tile 0 to buf0 ----
    stage_issue(Xr, Xd, B1, m0, tid, 0, a0, b0);
    stage_issue(Xr, Xd, B1, m0, tid, 1, a1, b1);
    stage_commit(out0, m0, tid, 0, a0, b0, &sA[0][0], &sB[0][0]);
    LGKM0(); BAR();

    for (int t = 0; t < 24; t += 2) {
        // ==== half A: compute tile t (buf0); prefetch t+2; commit t+1 ====
        if (t + 2 < 24) stage_issue(Xr, Xd, B1, m0, tid, t + 2, a0, b0);
        mfma_tile(&sA[0][0], &sB[0][0], wave, fr, fk, acc);
        BAR();                                        // all waves done reading buf0
        stage_commit(out0, m0, tid, t + 1, a1, b1, &sA[1][0], &sB[1][0]);
        LGKM0(); BAR();                               // buf1 ready

        // ==== half B: compute tile t+1 (buf1); prefetch t+3; commit t+2 ====
        if (t + 3 < 24) stage_issue(Xr, Xd, B1, m0, tid, t + 3, a1, b1);
        mfma_tile(&sA[1][0], &sB[1][0], wave, fr, fk, acc);
        if (t + 2 < 24) {
            BAR();                                    // all waves done reading buf1
            stage_commit(out0, m0, tid, t + 2, a0, b0, &sA[0][0], &sB[0][0]);
            LGKM0(); BAR();                           // buf0 ready
        }
    }

    // ---- epilogue: +bias, store bf16. C/D: row=(lane>>4)*4+r, col=lane&15 ----
    const int em = (lane >> 4) * 4, en = lane & 15;
#pragma unroll
    for (int j = 0; j < 6; j++) {
        int dcol = j * 16 + en;
        float bias = fb[dcol];
#pragma unroll
        for (int r = 0; r < 4; r++) {
            int row = m0 + wave * 16 + em + r;
            fbuf[(size_t)row * 96 + dcol] = f2b(acc[j][r] + bias);
        }
    }
}

// ============================================================
// gemm_o v2 (proven in R1): out1(32768 x 768) = fbuf @ Weff^T + b_out (fp32).
// LDS-free, barrier-free, 16384 waves. fbuf is bf16 in exact A-fragment
// layout -> direct 16B loads. Weff (147 KB) is L2-resident.
// ============================================================
__global__ __launch_bounds__(256) void gemm_o(const u16* __restrict__ fbuf,
                                              const u16* __restrict__ Weff,
                                              const float* __restrict__ bout,
                                              float* __restrict__ out1) {
    const int tid = threadIdx.x;
    const int lane = tid & 63;
    const int wv = (blockIdx.x << 2) | (tid >> 6);      // 0..16383
    const int mg = wv >> 3;                             // row-group 0..2047
    const int nc = (wv & 7) * 96;                       // col-chunk base
    const int fr = lane & 15, fk = (lane >> 4) << 3;

    const u16* pa = fbuf + (size_t)((mg << 4) | fr) * 96 + fk;
    bf16x8 A0 = *(const bf16x8*)(pa);
    bf16x8 A1 = *(const bf16x8*)(pa + 32);
    bf16x8 A2 = *(const bf16x8*)(pa + 64);

    const u16* pb = Weff + (size_t)(nc + fr) * 96 + fk;
    f32x4 acc[6] = {};
#pragma unroll
    for (int j = 0; j < 6; j++) {
        const u16* pbj = pb + j * 1536;                 // 16 rows x 96
        acc[j] = __builtin_amdgcn_mfma_f32_16x16x32_bf16(
            A0, *(const bf16x8*)(pbj), acc[j], 0, 0, 0);
        acc[j] = __builtin_amdgcn_mfma_f32_16x16x32_bf16(
            A1, *(const bf16x8*)(pbj + 32), acc[j], 0, 0, 0);
        acc[j] = __builtin_amdgcn_mfma_f32_16x16x32_bf16(
            A2, *(const bf16x8*)(pbj + 64), acc[j], 0, 0, 0);
    }

    const int em = (lane >> 4) << 2, en = lane & 15;
    const int orow = (mg << 4) + em;
#pragma unroll
    for (int j = 0; j < 6; j++) {
        const int col = nc + j * 16 + en;
        const float bias = bout[col];
#pragma unroll
        for (int r = 0; r < 4; r++)
            out1[(size_t)(orow + r) * 768 + col] = acc[j][r] + bias;
    }
}

// ============================================================
extern "C" void kernel_launch(void* const* d_in, const int* in_sizes, int n_in,
                              void* d_out, int out_size, void* d_ws, size_t ws_size,
                              hipStream_t stream) {
    const float* x_rgb       = (const float*)d_in[0];
    const float* x_depth     = (const float*)d_in[1];
    const float* W_qkv_rgb   = (const float*)d_in[2];
    const float* b_qkv_rgb   = (const float*)d_in[3];
    const float* W_qkv_depth = (const float*)d_in[4];
    const float* b_qkv_depth = (const float*)d_in[5];
    const float* W_out       = (const float*)d_in[6];
    const float* b_out       = (const float*)d_in[7];
    const float* aw          = (const float*)d_in[8];

    float* out0 = (float*)d_out;                      // x_rgb passthrough
    float* out1 = out0 + (size_t)M_TOT * 768;         // x_fusion

    // workspace layout (all 16B-aligned offsets); total ~6.8 MB
    char* w = (char*)d_ws;
    u16*   B1   = (u16*)w;                              // 96*1536*2   = 294912
    float* fb   = (float*)(w + 294912);                 // 96*4 (+pad) -> next at +512
    u16*   Weff = (u16*)(w + 294912 + 512);             // 768*96*2    = 147456
    u16*   fbuf = (u16*)(w + 294912 + 512 + 147456);    // 32768*96*2  = 6291456

    prep_b1<<<576, 256, 0, stream>>>(W_qkv_rgb, W_qkv_depth, b_qkv_rgb, b_qkv_depth,
                                     aw, B1, fb);
    prep_weff<<<288, 256, 0, stream>>>(W_out, Weff);
    gemm_f<<<512, 256, 0, stream>>>(x_rgb, x_depth, B1, fb, out0, fbuf);
    gemm_o<<<4096, 256, 0, stream>>>(fbuf, Weff, b_out, out1);
}